// Round 6
// baseline (203.611 us; speedup 1.0000x reference)
//
#include <hip/hip_runtime.h>

#define C_LEN 8192
#define Q_LEN 1024
#define DDIM  1024

typedef __attribute__((ext_vector_type(8))) short short8;
typedef __attribute__((ext_vector_type(4))) float f32x4;

// bf16 helpers (RNE)
static __device__ __forceinline__ unsigned short f2bf(float f){
  unsigned u = __float_as_uint(f);
  unsigned rounding = 0x7fffu + ((u >> 16) & 1u);
  return (unsigned short)((u + rounding) >> 16);
}

static __device__ __forceinline__ void async_copy16(const void* g, void* l){
  __builtin_amdgcn_global_load_lds(
      (const __attribute__((address_space(1))) void*)g,
      (__attribute__((address_space(3))) void*)l, 16, 0, 0);
}

static __device__ __forceinline__ float waveRedSum(float v){
  #pragma unroll
  for(int o=32;o;o>>=1) v += __shfl_down(v,o);
  return v;
}
static __device__ __forceinline__ float waveRedMax(float v){
  #pragma unroll
  for(int o=32;o;o>>=1) v = fmaxf(v,__shfl_down(v,o));
  return v;
}

// Merged prep: blocks [0,C_LEN) process H rows; [C_LEN, C_LEN+Q_LEN) process U rows.
__global__ void prep_HU(const float* __restrict__ H, const float* __restrict__ U,
                        const float* __restrict__ w_qc, const float* __restrict__ w_c,
                        const float* __restrict__ b_c, const float* __restrict__ w_q,
                        const float* __restrict__ b_q,
                        unsigned short* __restrict__ Abf, float* __restrict__ cterm,
                        float* __restrict__ eb, unsigned short* __restrict__ Ubf,
                        float* __restrict__ qterm, float* __restrict__ csum){
  const int b = blockIdx.x, t = threadIdx.x;
  __shared__ float sd[4], sm[4];
  const int w = t>>6, l = t&63;
  if(b < C_LEN){
    float4 h   = reinterpret_cast<const float4*>(H + (size_t)b*DDIM)[t];
    float4 wqc = reinterpret_cast<const float4*>(w_qc)[t];
    float4 wc  = reinterpret_cast<const float4*>(w_c)[t];
    float dot = h.x*wc.x + h.y*wc.y + h.z*wc.z + h.w*wc.w;
    float mx  = fmaxf(fmaxf(h.x,h.y), fmaxf(h.z,h.w));
    ushort4 o;
    o.x=f2bf(h.x*wqc.x); o.y=f2bf(h.y*wqc.y); o.z=f2bf(h.z*wqc.z); o.w=f2bf(h.w*wqc.w);
    reinterpret_cast<ushort4*>(Abf)[(size_t)b*256 + t] = o;
    dot = waveRedSum(dot); mx = waveRedMax(mx);
    if(l==0){ sd[w]=dot; sm[w]=mx; }
    __syncthreads();
    if(t==0){
      cterm[b] = sd[0]+sd[1]+sd[2]+sd[3] + b_c[0];
      float m = fmaxf(fmaxf(sm[0],sm[1]), fmaxf(sm[2],sm[3]));
      eb[b] = __expf(m);   // |rowmax| small -> exp safe without shift
    }
  } else {
    const int qr = b - C_LEN;
    float4 u  = reinterpret_cast<const float4*>(U + (size_t)qr*DDIM)[t];
    float4 wq = reinterpret_cast<const float4*>(w_q)[t];
    float dot = u.x*wq.x + u.y*wq.y + u.z*wq.z + u.w*wq.w;
    ushort4 o; o.x=f2bf(u.x); o.y=f2bf(u.y); o.z=f2bf(u.z); o.w=f2bf(u.w);
    reinterpret_cast<ushort4*>(Ubf)[(size_t)qr*256 + t] = o;
    dot = waveRedSum(dot);
    if(l==0) sd[w]=dot;
    __syncthreads();
    if(t==0){
      qterm[qr] = sd[0]+sd[1]+sd[2]+sd[3] + b_q[0];
      csum[qr]  = 0.f;
    }
  }
}

// Hpart[cb][d] = sum over 64 c's of eb[c]*H[c][d]   (512 blocks — was 128 at 0.5/CU)
__global__ void h_weighted(const float* __restrict__ H, const float* __restrict__ eb,
                           float* __restrict__ Hpart){
  int d  = blockIdx.x*256 + threadIdx.x;
  int cb = blockIdx.y, c0 = cb*64;
  float acc = 0.f;
  for(int c=c0;c<c0+64;c++)
    acc += eb[c] * H[(size_t)c*DDIM + d];
  Hpart[cb*DDIM + d] = acc;
}

// Hrow[d] = (sum_cb Hpart[cb][d]) / sum(eb)
__global__ void combine_Hrow(const float* __restrict__ Hpart, const float* __restrict__ eb,
                             float* __restrict__ Hrow){
  __shared__ float red[4];
  int t = threadIdx.x, w = t>>6, l = t&63;
  float s = 0.f;
  for(int i=t;i<C_LEN;i+=256) s += eb[i];
  s = waveRedSum(s);
  if(!l) red[w] = s;
  __syncthreads();
  float btot = red[0]+red[1]+red[2]+red[3];
  int d = blockIdx.x*256 + t;
  float acc = 0.f;
  #pragma unroll
  for(int p=0;p<128;p++) acc += Hpart[p*DDIM + d];
  Hrow[d] = acc / btot;
}

// Ut[d][q] = bf16(U[q][d] / csum[q]) — transpose + normalization fold
__global__ void transpose_scale_U(const float* __restrict__ U, const float* __restrict__ csum,
                                  unsigned short* __restrict__ Ut){
  __shared__ float tile[64][65];
  const int t = threadIdx.x;
  const int q0 = blockIdx.y*64, d0 = blockIdx.x*64;
  #pragma unroll
  for(int i=0;i<16;i++){
    int idx = i*256 + t, r = idx>>6, col = idx&63;
    tile[r][col] = U[(size_t)(q0+r)*DDIM + d0 + col];
  }
  float inv = 1.f / csum[q0 + (t&63)];
  __syncthreads();
  #pragma unroll
  for(int i=0;i<16;i++){
    int idx = i*256 + t, r = idx>>6, col = idx&63;
    Ut[(size_t)(d0+r)*Q_LEN + q0 + col] = f2bf(tile[col][r] * inv);
  }
}

// C[m][n] = sum_k A[m][k]*B[n][k]; bf16 in. Grid (64,8).
// 512 threads = 8 waves (2x4 of 64x32), 4x2 MFMA subtiles/wave -> 16 waves/CU
// at 2 blocks/CU (R5 post-mortem: 2 waves/SIMD left the K-loop latency-exposed).
// FUSE_EXP=1: out = bf16(exp(C + rowAdd[m] + colAdd[n] + addC)), csum[n] += col sums
// FUSE_EXP=0: out = f32 C; also writes H_toggler tile (rows = Hrow[bn..bn+128))
template<int FUSE_EXP>
__global__ __launch_bounds__(512, 4)
void gemm_bt(const unsigned short* __restrict__ A, const unsigned short* __restrict__ B,
             void* __restrict__ Cout, int M, int N, int K,
             const float* __restrict__ rowAdd, const float* __restrict__ colAdd,
             const float* __restrict__ addC, float* __restrict__ csum,
             const float* __restrict__ Hrow, float* __restrict__ outH){
  __shared__ unsigned short As[2][128][32];
  __shared__ unsigned short Bs[2][128][32];
  const int t = threadIdx.x;
  const int lane = t & 63, wave = t >> 6;   // 0..7
  const int wm = wave >> 2, wn = wave & 3;  // 2 x 4
  const int lr = lane & 15, quad = lane >> 4;
  // XCD-locality swizzle (speed-only heuristic)
  const int L = blockIdx.x + (blockIdx.y << 6);
  const int xcd = L & 7, r = L >> 3;
  const int by = r & 7, bx = ((r >> 3) << 3) | xcd;
  const int bm = bx * 128, bn = by * 128;
  const int srow = t >> 2;            // 0..127
  const int skcol = (t & 3) * 8;      // 16B chunks

  f32x4 acc[4][2];
  #pragma unroll
  for(int i=0;i<4;i++)
    #pragma unroll
    for(int j=0;j<2;j++) acc[i][j] = (f32x4){0.f,0.f,0.f,0.f};

  const unsigned short* gA = A + (size_t)(bm + srow)*K + skcol;
  const unsigned short* gB = B + (size_t)(bn + srow)*K + skcol;
  unsigned short* lA[2] = { &As[0][srow][skcol], &As[1][srow][skcol] };
  unsigned short* lB[2] = { &Bs[0][srow][skcol], &Bs[1][srow][skcol] };

  async_copy16(gA, lA[0]);
  async_copy16(gB, lB[0]);
  gA += 32; gB += 32;

  const int ITERS = K >> 5;
  for(int k=0;k<ITERS;k++){
    const int cur = k & 1, nxt = cur ^ 1;
    __syncthreads();
    if(k+1 < ITERS){
      async_copy16(gA, lA[nxt]);
      async_copy16(gB, lB[nxt]);
      gA += 32; gB += 32;
    }
    short8 af[4], bfr[2];
    #pragma unroll
    for(int i=0;i<4;i++)
      af[i]  = *reinterpret_cast<const short8*>(&As[cur][wm*64 + i*16 + lr][quad*8]);
    #pragma unroll
    for(int j=0;j<2;j++)
      bfr[j] = *reinterpret_cast<const short8*>(&Bs[cur][wn*32 + j*16 + lr][quad*8]);
    #pragma unroll
    for(int i=0;i<4;i++)
      #pragma unroll
      for(int j=0;j<2;j++)
        acc[i][j] = __builtin_amdgcn_mfma_f32_16x16x32_bf16(af[i], bfr[j], acc[i][j], 0,0,0);
  }

  const int col0 = bn + wn*32;
  if(FUSE_EXP){
    unsigned short* P = (unsigned short*)Cout;
    const float ac = addC[0];
    float cs[2];
    cs[0] = 0.f; cs[1] = 0.f;
    #pragma unroll
    for(int i=0;i<4;i++){
      int row0 = bm + wm*64 + i*16 + quad*4;
      float ra0 = rowAdd[row0], ra1 = rowAdd[row0+1], ra2 = rowAdd[row0+2], ra3 = rowAdd[row0+3];
      #pragma unroll
      for(int j=0;j<2;j++){
        int col = col0 + j*16 + lr;
        float cadd = colAdd[col] + ac;
        float e0 = __expf(acc[i][j][0] + ra0 + cadd);
        float e1 = __expf(acc[i][j][1] + ra1 + cadd);
        float e2 = __expf(acc[i][j][2] + ra2 + cadd);
        float e3 = __expf(acc[i][j][3] + ra3 + cadd);
        P[(size_t)(row0  )*N + col] = f2bf(e0);
        P[(size_t)(row0+1)*N + col] = f2bf(e1);
        P[(size_t)(row0+2)*N + col] = f2bf(e2);
        P[(size_t)(row0+3)*N + col] = f2bf(e3);
        cs[j] += e0+e1+e2+e3;
      }
    }
    #pragma unroll
    for(int j=0;j<2;j++){
      float v = cs[j];
      v += __shfl_xor(v, 16);
      v += __shfl_xor(v, 32);
      if(quad==0) atomicAdd(&csum[col0 + j*16 + lr], v);
    }
  } else {
    float* C = (float*)Cout;
    #pragma unroll
    for(int i=0;i<4;i++){
      int row0 = bm + wm*64 + i*16 + quad*4;
      #pragma unroll
      for(int j=0;j<2;j++){
        int col = col0 + j*16 + lr;
        #pragma unroll
        for(int rr=0;rr<4;rr++)
          C[(size_t)(row0+rr)*N + col] = acc[i][j][rr];
      }
    }
    // fused H_toggler tile: every row of [bm..bm+128) x [bn..bn+128) = Hrow[bn+..]
    float4 hv = reinterpret_cast<const float4*>(Hrow + bn)[t & 31];
    #pragma unroll
    for(int rr = t>>5; rr < 128; rr += 16)
      reinterpret_cast<float4*>(outH + (size_t)(bm+rr)*DDIM + bn)[t & 31] = hv;
  }
}

extern "C" void kernel_launch(void* const* d_in, const int* in_sizes, int n_in,
                              void* d_out, int out_size, void* d_ws, size_t ws_size,
                              hipStream_t stream){
  const float* H    = (const float*)d_in[0];
  const float* U    = (const float*)d_in[1];
  const float* w_q  = (const float*)d_in[2];
  const float* b_q  = (const float*)d_in[3];
  const float* w_c  = (const float*)d_in[4];
  const float* b_c  = (const float*)d_in[5];
  const float* w_qc = (const float*)d_in[6];
  const float* b_qc = (const float*)d_in[7];
  float* out = (float*)d_out;
  char*  ws  = (char*)d_ws;

  unsigned short* P    = (unsigned short*)(ws);                // 16 MB
  unsigned short* Abf  = (unsigned short*)(ws + 16777216);     // 16 MB
  unsigned short* Ubf  = (unsigned short*)(ws + 33554432);     //  2 MB
  unsigned short* Utb  = (unsigned short*)(ws + 35651584);     //  2 MB
  char* stats = ws + 37748736;
  float* csum  = (float*)(stats);           //  4 KB (zeroed by prep_HU)
  float* Hrow  = (float*)(stats + 4096);    //  4 KB
  float* cterm = (float*)(stats + 12288);   // 32 KB
  float* eb    = (float*)(stats + 45056);   // 32 KB
  float* qterm = (float*)(stats + 77824);   //  4 KB
  float* Hpart = (float*)(stats + 81920);   // 512 KB (128 partials)

  prep_HU<<<C_LEN + Q_LEN, 256, 0, stream>>>(H, U, w_qc, w_c, b_c, w_q, b_q,
                                             Abf, cterm, eb, Ubf, qterm, csum);

  h_weighted  <<<dim3(4,128), 256, 0, stream>>>(H, eb, Hpart);
  combine_Hrow<<<4, 256, 0, stream>>>(Hpart, eb, Hrow);

  gemm_bt<1><<<dim3(64,8), 512, 0, stream>>>(Abf, Ubf, (void*)P, C_LEN, Q_LEN, DDIM,
                                             cterm, qterm, b_qc, csum, nullptr, nullptr);

  transpose_scale_U<<<dim3(16,16), 256, 0, stream>>>(U, csum, Utb);

  gemm_bt<0><<<dim3(64,8), 512, 0, stream>>>(P, Utb, (void*)out, C_LEN, DDIM, Q_LEN,
                                             nullptr, nullptr, nullptr, nullptr,
                                             Hrow, out + (size_t)C_LEN*DDIM);
}